// Round 7
// baseline (575.337 us; speedup 1.0000x reference)
//
#include <hip/hip_runtime.h>
#include <hip/hip_bf16.h>
#include <stdint.h>

typedef __bf16 bf16x8 __attribute__((ext_vector_type(8)));
typedef float  f32x4  __attribute__((ext_vector_type(4)));
typedef unsigned short ushort8v __attribute__((ext_vector_type(8)));

#define NSLOPE 0.01f

// problem dims
#define NB   32
#define CIN  128
#define HIN  130
#define WIN  130
#define KOUT 256
#define POUT 128
#define QOUT 128
#define HWIN (HIN*WIN)            // 16900
#define PQ   (POUT*QOUT)

// workspace: X' (NHWC bf16) then W'' (fragment-packed bf16)
#define XP_BYTES 138444800ull     // 32*130*130*128*2
#define WP_ELEMS (18*2*8*2*64*8)  // 294912 bf16 = 589824 B

// LDS: X tile only, [130 w][64 ci] swizzled = 16640 B
#define LDS_TOTAL 16640

__device__ __forceinline__ unsigned short f2bf(float f) {
    unsigned u = __builtin_bit_cast(unsigned, f);
    u += 0x7FFFu + ((u >> 16) & 1u);   // RNE
    return (unsigned short)(u >> 16);
}

__device__ __forceinline__ void g2lds16(const void* g, void* l) {
    __builtin_amdgcn_global_load_lds(
        (const __attribute__((address_space(1))) void*)g,
        (__attribute__((address_space(3))) void*)l,
        16, 0, 0);
}

// ---------------- pre-pass 1: X NCHW fp32 -> NHWC bf16 (vectorized) ----------------
__global__ __launch_bounds__(256) void k_conv_x(const float* __restrict__ X,
                                                unsigned short* __restrict__ Xp) {
    __shared__ unsigned short tile[130*132];   // [w][c], c padded 128->132
    const int b = blockIdx.x;                  // n*130 + h
    const int n = b / 130, h = b - n*130;
    const int tid = threadIdx.x;
    const size_t in_base = (size_t)n*(CIN*(size_t)HWIN) + (size_t)h*WIN;
    for (int fi = tid; fi < CIN*65; fi += 256) {
        int c = fi / 65, w2 = fi - c*65;
        float2 v = *(const float2*)(X + in_base + (size_t)c*HWIN + w2*2);
        tile[(w2*2  )*132 + c] = f2bf(v.x);
        tile[(w2*2+1)*132 + c] = f2bf(v.y);
    }
    __syncthreads();
    unsigned short* outp = Xp + (size_t)b * (WIN*CIN);
    for (int oi = tid; oi < (WIN*CIN)/8; oi += 256) {
        int e = oi*8; int w = e >> 7; int c8 = e & 127;
        const unsigned short* t = &tile[w*132 + c8];
        ushort8v v;
        #pragma unroll
        for (int j = 0; j < 8; ++j) v[j] = t[j];
        *(ushort8v*)(outp + e) = v;
    }
}

// ---------------- pre-pass 2: W OIHW fp32 -> W'' fragment-packed (verified in R5) ----------------
// element e: j=e&7, lane=(e>>3)&63, kq=(e>>9)&1, fr=(e>>10)&7, kh=(e>>13)&1, rsidx=e>>14
// value = W[kout = kh*128+fr*16+(lane&15)][ci = cc*64+kq*32+(lane>>4)*8+j][rr][s]
__global__ __launch_bounds__(256) void k_conv_w(const float* __restrict__ W,
                                                unsigned short* __restrict__ Wp) {
    int e = blockIdx.x*256 + threadIdx.x;
    if (e >= WP_ELEMS) return;
    int j     = e & 7;
    int lane  = (e >> 3) & 63;
    int kq    = (e >> 9) & 1;
    int fr    = (e >> 10) & 7;
    int kh    = (e >> 13) & 1;
    int rsidx = e >> 14;                       // 0..17
    int cc = rsidx / 9; int rem = rsidx - cc*9; int rr = rem / 3, s = rem - rr*3;
    int kout = kh*128 + fr*16 + (lane & 15);
    int ci   = cc*64 + kq*32 + (lane >> 4)*8 + j;
    Wp[e] = f2bf(W[(size_t)kout*1152 + (size_t)ci*9 + rr*3 + s]);
}

// ---------------- main conv: 128 kout x 128 q blocks, 2 waves of 64x128 ----------------
// A (W'') direct global->VGPR from L2 (fragment-packed, 1024-B wave loads);
// B (X) via swizzled LDS tile, staged once per (cc,r), reused across s.
// swizzle: phys = logical ^ ((row&7)<<4), rows are 128 B
__global__ __launch_bounds__(128, 2) void k_conv_main(
    const unsigned short* __restrict__ Xp,
    const unsigned short* __restrict__ Wpp,
    const float* __restrict__ bias,
    float* __restrict__ out)
{
    __shared__ __align__(16) unsigned char xs[LDS_TOTAL];

    const int tid  = threadIdx.x;
    const int lane = tid & 63;
    const int wm   = tid >> 6;        // 0..1: kout 64-block within the kh-half
    const int l15  = lane & 15;
    const int kg16 = (lane >> 4) << 4;
    const int laneB = lane << 4;

    // grid 8192 = 8 XCD-chunks x 1024; L = n*256 + p*2 + kh (kh pairs adjacent, same XCD)
    const int L  = ((blockIdx.x & 7) << 10) | (blockIdx.x >> 3);
    const int kh = L & 1;
    const int np = L >> 1;
    const int p  = np & 127;
    const int n  = np >> 7;

    const unsigned char* wfp = (const unsigned char*)Wpp + (kh << 14) + (wm << 13) + laneB;

    f32x4 acc[4][8];
    #pragma unroll
    for (int i = 0; i < 4; ++i)
        #pragma unroll
        for (int j = 0; j < 8; ++j)
            acc[i][j] = (f32x4){0.f, 0.f, 0.f, 0.f};

    #pragma unroll 1
    for (int cr = 0; cr < 6; ++cr) {
        const int cc = cr / 3;
        const int r  = cr - cc*3;

        __syncthreads();   // previous (cc,r)'s reads complete before overwrite
        {   // stage X(cc, p+r): 1040 granules over 128 threads
            const unsigned short* xbase =
                Xp + ((size_t)((n*HIN + (p + r))*WIN))*CIN + cc*64;
            #pragma unroll
            for (int it = 0; it < 9; ++it) {
                const int g = it*128 + tid;
                if (g < 1040) {
                    const int phys = g << 4;
                    const int w    = phys >> 7;                  // 0..129
                    const int cib  = (phys & 127) ^ ((w & 7) << 4);
                    g2lds16(xbase + (size_t)w*CIN + (cib >> 1), xs + phys);
                }
            }
        }
        __syncthreads();   // drains vmcnt: X tile ready

        #pragma unroll
        for (int s = 0; s < 3; ++s) {
            const unsigned char* wb = wfp + (size_t)(cr*3 + s)*32768;
            #pragma unroll
            for (int kq = 0; kq < 2; ++kq) {
                bf16x8 A[4], B[8];
                #pragma unroll
                for (int mf = 0; mf < 4; ++mf)
                    A[mf] = *(const bf16x8*)(wb + kq*1024 + mf*2048);
                const int cib0 = kq*64 + kg16;
                #pragma unroll
                for (int nf = 0; nf < 8; ++nf) {
                    const int g = nf*16 + l15 + s;               // w = q + s
                    B[nf] = *(const bf16x8*)(xs + g*128 + (cib0 ^ ((g & 7) << 4)));
                }
                #pragma unroll
                for (int mf = 0; mf < 4; ++mf)
                    #pragma unroll
                    for (int nf = 0; nf < 8; ++nf)
                        acc[mf][nf] = __builtin_amdgcn_mfma_f32_16x16x32_bf16(
                            A[mf], B[nf], acc[mf][nf], 0, 0, 0);
            }
        }
    }

    // epilogue: D col(q) = lane&15, row(kout) = kg*4 + j -> coalesced 64-B segments
    const int kg = lane >> 4;
    #pragma unroll
    for (int mf = 0; mf < 4; ++mf) {
        const int kb = kh*128 + wm*64 + mf*16 + kg*4;
        const float4 bv = *(const float4*)(bias + kb);
        const float bj[4] = {bv.x, bv.y, bv.z, bv.w};
        #pragma unroll
        for (int nf = 0; nf < 8; ++nf) {
            const int q = nf*16 + l15;
            const size_t base = (((size_t)n*KOUT + kb)*POUT + p)*QOUT + q;
            #pragma unroll
            for (int j = 0; j < 4; ++j) {
                float y = (acc[mf][nf][j] + bj[j]) * 0.5f;
                out[base + (size_t)j*PQ] = (y >= 0.f) ? y : y*NSLOPE;
            }
        }
    }
}

extern "C" void kernel_launch(void* const* d_in, const int* in_sizes, int n_in,
                              void* d_out, int out_size, void* d_ws, size_t ws_size,
                              hipStream_t stream) {
    const float* X = (const float*)d_in[0];
    const float* W = (const float*)d_in[1];
    const float* B = (const float*)d_in[2];
    float* out = (float*)d_out;
    unsigned short* Xp = (unsigned short*)d_ws;
    unsigned short* Wp = (unsigned short*)((char*)d_ws + XP_BYTES);

    k_conv_x   <<<NB*HIN, 256, 0, stream>>>(X, Xp);
    k_conv_w   <<<(WP_ELEMS + 255)/256, 256, 0, stream>>>(W, Wp);
    k_conv_main<<<8192, 128, 0, stream>>>(Xp, Wp, B, out);
}